// Round 5
// baseline (357.492 us; speedup 1.0000x reference)
//
#include <hip/hip_runtime.h>
#include <math.h>

#define VOCAB 32000
#define EMBED 512
#define HID   1024
#define BATCH 64
#define SEQ   512

// d_out layout (floats): pred[64*32000]=0 .. 2048000 ; h1 @2048000 ; c1 @2113536 ; attn @2179072
#define OUT_H1   2048000
#define OUT_C1   2113536
#define OUT_ATTN 2179072

typedef __bf16 bf16x8 __attribute__((ext_vector_type(8)));
typedef float  f32x4  __attribute__((ext_vector_type(4)));

__device__ __forceinline__ unsigned short f2bf(float f) {
  unsigned int u = __builtin_bit_cast(unsigned int, f);
  u += 0x7fffu + ((u >> 16) & 1u);   // round-to-nearest-even
  return (unsigned short)(u >> 16);
}
__device__ __forceinline__ float bf2f(unsigned int u) {
  return __builtin_bit_cast(float, u << 16);
}

// async 16B/lane global->LDS; lds ptr must be wave-uniform (HW: base + lane*16)
__device__ __forceinline__ void gload16(const unsigned short* g, unsigned short* l) {
  __builtin_amdgcn_global_load_lds(
      (const __attribute__((address_space(1))) void*)g,
      (__attribute__((address_space(3))) void*)l, 16, 0, 0);
}

// 16 f32 -> 16 bf16 (RNE bit-trick), 32B to LDS
__device__ __forceinline__ void stage16(const float* __restrict__ src, unsigned short* dst) {
  float4 f0 = *(const float4*)(src + 0);
  float4 f1 = *(const float4*)(src + 4);
  float4 f2 = *(const float4*)(src + 8);
  float4 f3 = *(const float4*)(src + 12);
  union { unsigned short us[16]; uint4 u4[2]; } p;
  p.us[0]=f2bf(f0.x);  p.us[1]=f2bf(f0.y);  p.us[2]=f2bf(f0.z);  p.us[3]=f2bf(f0.w);
  p.us[4]=f2bf(f1.x);  p.us[5]=f2bf(f1.y);  p.us[6]=f2bf(f1.z);  p.us[7]=f2bf(f1.w);
  p.us[8]=f2bf(f2.x);  p.us[9]=f2bf(f2.y);  p.us[10]=f2bf(f2.z); p.us[11]=f2bf(f2.w);
  p.us[12]=f2bf(f3.x); p.us[13]=f2bf(f3.y); p.us[14]=f2bf(f3.z); p.us[15]=f2bf(f3.w);
  *(uint4*)(dst + 0) = p.u4[0];
  *(uint4*)(dst + 8) = p.u4[1];
}

// ------------- f32 -> bf16 bulk convert (grid-stride, 8 elems/thread/iter) -------------
__global__ void f2bf_kernel(const float* __restrict__ src, unsigned short* __restrict__ dst,
                            int n8) {
  int i = blockIdx.x * blockDim.x + threadIdx.x;
  int stride = gridDim.x * blockDim.x;
  for (; i < n8; i += stride) {
    const float* s = src + (size_t)i * 8;
    float4 f0 = *(const float4*)s;
    float4 f1 = *(const float4*)(s + 4);
    union { unsigned short us[8]; uint4 u; } p;
    p.us[0]=f2bf(f0.x); p.us[1]=f2bf(f0.y); p.us[2]=f2bf(f0.z); p.us[3]=f2bf(f0.w);
    p.us[4]=f2bf(f1.x); p.us[5]=f2bf(f1.y); p.us[6]=f2bf(f1.z); p.us[7]=f2bf(f1.w);
    *(uint4*)(dst + (size_t)i * 8) = p.u;
  }
}

// ---------------- dh = h0 @ W1^T  (64x1024, K=1024) ----------------
__global__ void dh_kernel(const float* __restrict__ h0, const float* __restrict__ W1,
                          float* __restrict__ dh) {
  __shared__ float hs[HID];
  int b = blockIdx.y, t = threadIdx.x;
  for (int i = t; i < HID; i += 256) hs[i] = h0[b * HID + i];
  __syncthreads();
  int k = blockIdx.x * 256 + t;
  const float* w = W1 + (size_t)k * HID;
  float acc = 0.f;
  for (int hh = 0; hh < HID; hh += 4) {
    float4 wv = *(const float4*)(w + hh);
    float4 hv = *(const float4*)(hs + hh);
    acc += wv.x * hv.x + wv.y * hv.y + wv.z * hv.z + wv.w * hv.w;
  }
  dh[b * HID + k] = acc;
}

// ==== scores v4: 256x256 tile, BK=64, 8 waves; hoisted reads + early stage ====
// eh = enc@W2^T fused with  scores += sum_n v[n]*tanh(dh[b,n]+eh)  (atomicAdd)
// LDS swizzle: byte ^= ((byte>>8)&3)<<4 (1KB-stripe involution), applied via
// pre-swizzled GLOBAL source (gload_lds writes linearly) + swizzled ds_read.
__launch_bounds__(512, 2)
__global__ void scores8_kernel(const unsigned short* __restrict__ encb,
                               const unsigned short* __restrict__ W2b,
                               const float* __restrict__ dh, const float* __restrict__ v,
                               float* __restrict__ scores) {
  __shared__ __align__(16) unsigned short sA[2][16384];  // [dbuf][256 rows * 64 k]
  __shared__ __align__(16) unsigned short sB[2][16384];
  __shared__ float dh_s[256];
  __shared__ float v_s[256];

  // bijective XCD-chunked swizzle: 512 wgs, 64/XCD; one m-panel's 4 n-tiles
  // are consecutive on one XCD -> A-panel L2-resident.
  int bid = blockIdx.x;
  int wg = (bid & 7) * 64 + (bid >> 3);
  int mt = wg >> 2, nt = wg & 3;
  int m0 = mt * 256, n0 = nt * 256;

  int t = threadIdx.x;
  int wid = t >> 6, l = t & 63;
  int wr = wid >> 2, wc = wid & 3;     // 2 M-waves x 4 N-waves
  int fr = l & 15, co = (l >> 4) * 8;

  // Stage-source: chunk c covers rows [c*64, c*64+64). Swizzle bits (8,9) come
  // entirely from the intra-chunk byte offset, so chunk sources differ by the
  // uniform constant c*64*HID elements.
  const unsigned short* pa0;
  const unsigned short* pb0;
  int do0 = wid * 512;  // LDS elem offset of this wave's 1KB slice in chunk 0
  {
    int base = wid * 1024 + l * 16;                 // byte offset in chunk 0
    int srel = base ^ (((base >> 8) & 3) << 4);     // involution
    int row = srel >> 7, colE = (srel >> 1) & 63;
    pa0 = encb + (size_t)(m0 + row) * HID + colE;
    pb0 = W2b + (size_t)(n0 + row) * HID + colE;
  }

  f32x4 acc[8][4];
#pragma unroll
  for (int i = 0; i < 8; i++)
#pragma unroll
    for (int j = 0; j < 4; j++) acc[i][j] = (f32x4){0.f, 0.f, 0.f, 0.f};

#define SC_STAGE(T, d)                                                         \
  do {                                                                         \
    int k0_ = (T) * 64;                                                        \
    gload16(pa0 + k0_,          &sA[d][do0]);                                  \
    gload16(pa0 + 65536 + k0_,  &sA[d][do0 + 4096]);                           \
    gload16(pa0 + 131072 + k0_, &sA[d][do0 + 8192]);                           \
    gload16(pa0 + 196608 + k0_, &sA[d][do0 + 12288]);                          \
    gload16(pb0 + k0_,          &sB[d][do0]);                                  \
    gload16(pb0 + 65536 + k0_,  &sB[d][do0 + 4096]);                           \
    gload16(pb0 + 131072 + k0_, &sB[d][do0 + 8192]);                           \
    gload16(pb0 + 196608 + k0_, &sB[d][do0 + 12288]);                          \
  } while (0)

  SC_STAGE(0, 0);
  SC_STAGE(1, 1);

  // swizzled ds_read: elem col ^= ((row>>1)&3)<<3
#define LDF(Mat, row, ks) \
  (*(const bf16x8*)&Mat[(row) * 64 + (((ks) * 32 + co) ^ ((((row) >> 1) & 3) << 3))])

  for (int T = 0; T < 16; ++T) {
    int d = T & 1;
    if (T == 15) asm volatile("s_waitcnt vmcnt(0)" ::: "memory");
    else         asm volatile("s_waitcnt vmcnt(8)" ::: "memory");
    asm volatile("s_barrier" ::: "memory");
    const unsigned short* A = sA[d];
    const unsigned short* B = sB[d];
    bf16x8 a[8][2], b[4][2];
#pragma unroll
    for (int jj = 0; jj < 4; ++jj)
#pragma unroll
      for (int ks = 0; ks < 2; ++ks)
        b[jj][ks] = LDF(B, wc * 64 + jj * 16 + fr, ks);
#pragma unroll
    for (int ii = 0; ii < 8; ++ii)
#pragma unroll
      for (int ks = 0; ks < 2; ++ks)
        a[ii][ks] = LDF(A, wr * 128 + ii * 16 + fr, ks);
    asm volatile("s_waitcnt lgkmcnt(0)" ::: "memory");
    asm volatile("s_barrier" ::: "memory");   // all waves' reads of dbuf d done
    if (T < 14) SC_STAGE(T + 2, d);           // overlaps with MFMA below
    // 4 MFMA clusters (16 each)
    __builtin_amdgcn_s_setprio(1);
#pragma unroll
    for (int ii = 0; ii < 4; ++ii)
#pragma unroll
      for (int jj = 0; jj < 2; ++jj)
#pragma unroll
        for (int ks = 0; ks < 2; ++ks)
          acc[ii][jj] = __builtin_amdgcn_mfma_f32_16x16x32_bf16(a[ii][ks], b[jj][ks], acc[ii][jj], 0, 0, 0);
    __builtin_amdgcn_s_setprio(0);
    __builtin_amdgcn_s_setprio(1);
#pragma unroll
    for (int ii = 0; ii < 4; ++ii)
#pragma unroll
      for (int jj = 2; jj < 4; ++jj)
#pragma unroll
        for (int ks = 0; ks < 2; ++ks)
          acc[ii][jj] = __builtin_amdgcn_mfma_f32_16x16x32_bf16(a[ii][ks], b[jj][ks], acc[ii][jj], 0, 0, 0);
    __builtin_amdgcn_s_setprio(0);
    __builtin_amdgcn_s_setprio(1);
#pragma unroll
    for (int ii = 4; ii < 8; ++ii)
#pragma unroll
      for (int jj = 2; jj < 4; ++jj)
#pragma unroll
        for (int ks = 0; ks < 2; ++ks)
          acc[ii][jj] = __builtin_amdgcn_mfma_f32_16x16x32_bf16(a[ii][ks], b[jj][ks], acc[ii][jj], 0, 0, 0);
    __builtin_amdgcn_s_setprio(0);
    __builtin_amdgcn_s_setprio(1);
#pragma unroll
    for (int ii = 4; ii < 8; ++ii)
#pragma unroll
      for (int jj = 0; jj < 2; ++jj)
#pragma unroll
        for (int ks = 0; ks < 2; ++ks)
          acc[ii][jj] = __builtin_amdgcn_mfma_f32_16x16x32_bf16(a[ii][ks], b[jj][ks], acc[ii][jj], 0, 0, 0);
    __builtin_amdgcn_s_setprio(0);
  }
#undef LDF
#undef SC_STAGE

  // epilogue: partial scores over this 256-wide n-tile
  int b = m0 >> 9;  // 256 | 512 so tile lies in one batch row
  if (t < 256) { dh_s[t] = dh[b * HID + n0 + t]; v_s[t] = v[n0 + t]; }
  __syncthreads();
  float sp[32];
#pragma unroll
  for (int q = 0; q < 32; ++q) sp[q] = 0.f;
#pragma unroll
  for (int ii = 0; ii < 8; ++ii)
#pragma unroll
    for (int jj = 0; jj < 4; ++jj) {
      int nl = wc * 64 + jj * 16 + fr;
      float dv = dh_s[nl], vv = v_s[nl];
#pragma unroll
      for (int r = 0; r < 4; ++r)
        sp[ii * 4 + r] += tanhf(dv + acc[ii][jj][r]) * vv;
    }
#pragma unroll
  for (int q = 0; q < 32; ++q) {
    float x = sp[q];
    x += __shfl_xor(x, 1);
    x += __shfl_xor(x, 2);
    x += __shfl_xor(x, 4);
    x += __shfl_xor(x, 8);
    sp[q] = x;
  }
  if (fr == 0) {
    int rbase = m0 + wr * 128 + (l >> 4) * 4;
#pragma unroll
    for (int ii = 0; ii < 8; ++ii)
#pragma unroll
      for (int r = 0; r < 4; ++r)
        atomicAdd(&scores[rbase + ii * 16 + r], sp[ii * 4 + r]);
  }
}

// ---------------- softmax over S per batch row ----------------
__global__ void softmax_kernel(const float* __restrict__ scores, float* __restrict__ attn) {
  __shared__ float red[8];
  int b = blockIdx.x, t = threadIdx.x;  // 512 threads
  float x = scores[b * SEQ + t];
  float m = x;
  for (int d = 1; d < 64; d <<= 1) m = fmaxf(m, __shfl_xor(m, d));
  if ((t & 63) == 0) red[t >> 6] = m;
  __syncthreads();
  float bm = red[0];
#pragma unroll
  for (int i = 1; i < 8; i++) bm = fmaxf(bm, red[i]);
  float e = expf(x - bm);
  float s = e;
  for (int d = 1; d < 64; d <<= 1) s += __shfl_xor(s, d);
  __syncthreads();
  if ((t & 63) == 0) red[t >> 6] = s;
  __syncthreads();
  float bs = 0.f;
#pragma unroll
  for (int i = 0; i < 8; i++) bs += red[i];
  attn[b * SEQ + t] = e / bs;
}

// ------- context: bf16 enc, 16B/lane; ctx[b,h] = sum_s attn[b,s]*enc[b,s,h] -------
__global__ void context2_kernel(const unsigned short* __restrict__ encb,
                                const float* __restrict__ attn, float* __restrict__ ctx) {
  __shared__ float a_s[64];
  int b = blockIdx.y, s0 = blockIdx.x * 64, t = threadIdx.x;
  if (t < 64) a_s[t] = attn[b * SEQ + s0 + t];
  __syncthreads();
  int hg = (t & 127) * 8, sg = (t >> 7) * 32;  // 128 h-threads x 2 s-groups
  float a0 = 0.f, a1 = 0.f, a2 = 0.f, a3 = 0.f, a4 = 0.f, a5 = 0.f, a6 = 0.f, a7 = 0.f;
  const unsigned short* base = encb + ((size_t)b * SEQ + s0 + sg) * HID + hg;
  for (int s = 0; s < 32; s++) {
    uint4 ev = *(const uint4*)(base + (size_t)s * HID);
    float a = a_s[sg + s];
    a0 += a * bf2f(ev.x & 0xffffu); a1 += a * bf2f(ev.x >> 16);
    a2 += a * bf2f(ev.y & 0xffffu); a3 += a * bf2f(ev.y >> 16);
    a4 += a * bf2f(ev.z & 0xffffu); a5 += a * bf2f(ev.z >> 16);
    a6 += a * bf2f(ev.w & 0xffffu); a7 += a * bf2f(ev.w >> 16);
  }
  atomicAdd(&ctx[b * HID + hg + 0], a0);
  atomicAdd(&ctx[b * HID + hg + 1], a1);
  atomicAdd(&ctx[b * HID + hg + 2], a2);
  atomicAdd(&ctx[b * HID + hg + 3], a3);
  atomicAdd(&ctx[b * HID + hg + 4], a4);
  atomicAdd(&ctx[b * HID + hg + 5], a5);
  atomicAdd(&ctx[b * HID + hg + 6], a6);
  atomicAdd(&ctx[b * HID + hg + 7], a7);
}

// ---- gates (xcat fused): gates[b,j] += x[b,:]·[W_ih|W_hh][j,:], K-split 8 ----
// x = [emb[tok[b]] (512) | ctx[b] (1024) | h0[b] (1024)]
__launch_bounds__(256)
__global__ void gates_kernel(const int* __restrict__ tok, const float* __restrict__ emb,
                             const float* __restrict__ ctx, const float* __restrict__ h0,
                             const float* __restrict__ W_ih, const float* __restrict__ W_hh,
                             float* __restrict__ gates) {
  __shared__ float xk[64 * 33];
  __shared__ float wk[64 * 33];
  int j0 = blockIdx.x * 64, kz = blockIdx.y, t = threadIdx.x;
  int b0 = (t >> 6) * 16, jj = t & 63;
  int rowX = t >> 2, qk = (t & 3) * 8;
  int tk = tok[rowX];
  float acc[16];
#pragma unroll
  for (int i = 0; i < 16; i++) acc[i] = 0.f;
  for (int ks = 0; ks < 10; ks++) {
    int k0 = kz * 320 + ks * 32;
    __syncthreads();
    {
      int kg = k0 + qk;  // 8-elem segment never crosses 512/1536
      const float* src;
      if (kg < 512)        src = emb + (size_t)tk * EMBED + kg;
      else if (kg < 1536)  src = ctx + rowX * HID + (kg - 512);
      else                 src = h0 + rowX * HID + (kg - 1536);
#pragma unroll
      for (int i = 0; i < 8; i++) xk[rowX * 33 + qk + i] = src[i];
    }
    {
      int j = j0 + rowX;
      int kg = k0 + qk;
      const float* src = (kg < 1536) ? (W_ih + (size_t)j * 1536 + kg)
                                     : (W_hh + (size_t)j * 1024 + (kg - 1536));
#pragma unroll
      for (int i = 0; i < 8; i++) wk[rowX * 33 + qk + i] = src[i];
    }
    __syncthreads();
#pragma unroll
    for (int kk = 0; kk < 32; kk++) {
      float wv = wk[jj * 33 + kk];
#pragma unroll
      for (int bb = 0; bb < 16; bb++) acc[bb] += xk[(b0 + bb) * 33 + kk] * wv;
    }
  }
#pragma unroll
  for (int bb = 0; bb < 16; bb++)
    atomicAdd(&gates[(size_t)(b0 + bb) * 4096 + j0 + jj], acc[bb]);
}

// ---------------- LSTM pointwise -> h1, c1 ----------------
__global__ void lstm_kernel(const float* __restrict__ gates, const float* __restrict__ b_ih,
                            const float* __restrict__ b_hh, const float* __restrict__ c0,
                            float* __restrict__ out) {
  int b = blockIdx.y;
  int hh = blockIdx.x * 256 + threadIdx.x;
  const float* g = gates + (size_t)b * 4096;
  float gi = g[hh]        + b_ih[hh]        + b_hh[hh];
  float gf = g[1024 + hh] + b_ih[1024 + hh] + b_hh[1024 + hh];
  float gg = g[2048 + hh] + b_ih[2048 + hh] + b_hh[2048 + hh];
  float go = g[3072 + hh] + b_ih[3072 + hh] + b_hh[3072 + hh];
  float si = 1.f / (1.f + expf(-gi));
  float sf = 1.f / (1.f + expf(-gf));
  float so = 1.f / (1.f + expf(-go));
  float c1 = sf * c0[b * HID + hh] + si * tanhf(gg);
  float h1 = so * tanhf(c1);
  out[OUT_H1 + b * HID + hh] = h1;
  out[OUT_C1 + b * HID + hh] = c1;
}

// ---- fc: K-split x4, partial planes (no atomics) ----
// part[kq] = A_kq @ fc_W[:, kq*512:+512]^T   (M=64, N=32000, K=512 each)
__launch_bounds__(256)
__global__ void fc4p_kernel(const float* __restrict__ h1, const float* __restrict__ ctx,
                            const float* __restrict__ fcW, float* __restrict__ part) {
  __shared__ __align__(16) unsigned short lA[64 * 40];
  __shared__ __align__(16) unsigned short lB[128 * 40];
  int n0 = blockIdx.x * 128, kq = blockIdx.y;      // kq: K quarter (512 wide)
  const float* A = (kq < 2) ? h1 : ctx;
  int aoff = (kq & 1) * 512;
  int t = threadIdx.x, w = t >> 6, l = t & 63;
  f32x4 acc[4][2];
#pragma unroll
  for (int i = 0; i < 4; i++)
#pragma unroll
    for (int j = 0; j < 2; j++) acc[i][j] = (f32x4){0.f, 0.f, 0.f, 0.f};
  int rowA = t >> 2, qA = (t & 3) * 8;   // 64 rows x 4 quads of 8
  int rowB = t >> 1, hB = t & 1;         // 128 rows x 2 halves of 16

  for (int kt = 0; kt < 16; kt++) {
    int k0 = kt * 32;
    {  // A stage: 8 floats -> 8 bf16 (RNE bit-trick)
      const float* src = A + rowA * HID + aoff + k0 + qA;
      float4 f0 = *(const float4*)src;
      float4 f1 = *(const float4*)(src + 4);
      union { unsigned short us[8]; uint4 u; } p;
      p.us[0]=f2bf(f0.x); p.us[1]=f2bf(f0.y); p.us[2]=f2bf(f0.z); p.us[3]=f2bf(f0.w);
      p.us[4]=f2bf(f1.x); p.us[5]=f2bf(f1.y); p.us[6]=f2bf(f1.z); p.us[7]=f2bf(f1.w);
      *(uint4*)&lA[rowA * 40 + qA] = p.u;
    }
    stage16(fcW + (size_t)(n0 + rowB) * 2048 + kq * 512 + k0 + hB * 16,
            &lB[rowB * 40 + hB * 16]);
    __syncthreads();
    bf16x8 af[4], bv[2];
    int co = (l >> 4) * 8;
#pragma unroll
    for (int i = 0; i < 4; i++) af[i] = *(const bf16x8*)&lA[(i * 16 + (l & 15)) * 40 + co];
#pragma unroll
    for (int j = 0; j < 2; j++) bv[j] = *(const bf16x8*)&lB[(w * 32 + j * 16 + (l & 15)) * 40 + co];
#pragma unroll
    for (int i = 0; i < 4; i++)
#pragma unroll
      for (int j = 0; j < 2; j++)
        acc[i][j] = __builtin_amdgcn_mfma_f32_16x16x32_bf16(af[i], bv[j], acc[i][j], 0, 0, 0);
    __syncthreads();
  }
#pragma unroll
  for (int i = 0; i < 4; i++)
#pragma unroll
    for (int j = 0; j < 2; j++) {
      int n = n0 + w * 32 + j * 16 + (l & 15);
#pragma unroll
      for (int r = 0; r < 4; r++) {
        int m = i * 16 + (l >> 4) * 4 + r;
        part[(size_t)kq * 2048000 + (size_t)m * VOCAB + n] = acc[i][j][r];
      }
    }
}

__global__ void fc_combine_kernel(const float* __restrict__ part,
                                  const float* __restrict__ fcb, float* __restrict__ pred) {
  int n = blockIdx.x * 256 + threadIdx.x;   // 125*256 = 32000
  int m = blockIdx.y;
  size_t i = (size_t)m * VOCAB + n;
  pred[i] = part[i] + part[2048000 + i] + part[4096000 + i] + part[6144000 + i] + fcb[n];
}

extern "C" void kernel_launch(void* const* d_in, const int* in_sizes, int n_in,
                              void* d_out, int out_size, void* d_ws, size_t ws_size,
                              hipStream_t stream) {
  const int*   tok  = (const int*)d_in[0];
  const float* h    = (const float*)d_in[1];
  const float* c    = (const float*)d_in[2];
  const float* enc  = (const float*)d_in[3];
  const float* emb  = (const float*)d_in[4];
  const float* W1   = (const float*)d_in[5];
  const float* W2   = (const float*)d_in[6];
  const float* v    = (const float*)d_in[7];
  const float* W_ih = (const float*)d_in[8];
  const float* W_hh = (const float*)d_in[9];
  const float* b_ih = (const float*)d_in[10];
  const float* b_hh = (const float*)d_in[11];
  const float* fcW  = (const float*)d_in[12];
  const float* fcb  = (const float*)d_in[13];
  float* out = (float*)d_out;

  float* wsf    = (float*)d_ws;
  float* scores = wsf;             // 32768
  float* ctx    = wsf + 32768;     // 65536
  float* gates  = wsf + 98304;     // 262144
  float* dh     = wsf + 360448;    // 65536
  float* part   = wsf + 425984;    // 4*2048000
  unsigned short* encb = (unsigned short*)(wsf + 8617984);   // 33,554,432 bf16
  unsigned short* W2b  = encb + (size_t)BATCH * SEQ * HID;   //  1,048,576 bf16

  // zero scores+ctx+gates (atomic accumulation targets)
  hipMemsetAsync(wsf, 0, (size_t)360448 * sizeof(float), stream);

  f2bf_kernel<<<2048, 256, 0, stream>>>(enc, encb, BATCH * SEQ * HID / 8);
  f2bf_kernel<<<512, 256, 0, stream>>>(W2, W2b, HID * HID / 8);
  dh_kernel<<<dim3(4, 64), 256, 0, stream>>>(h, W1, dh);
  scores8_kernel<<<512, 512, 0, stream>>>(encb, W2b, dh, v, scores);
  softmax_kernel<<<64, 512, 0, stream>>>(scores, out + OUT_ATTN);
  context2_kernel<<<dim3(8, 64), 256, 0, stream>>>(encb, out + OUT_ATTN, ctx);
  gates_kernel<<<dim3(64, 8), 256, 0, stream>>>(tok, emb, ctx, h, W_ih, W_hh, gates);
  lstm_kernel<<<dim3(4, 64), 256, 0, stream>>>(gates, b_ih, b_hh, c, out);
  fc4p_kernel<<<dim3(250, 4), 256, 0, stream>>>(out + OUT_H1, ctx, fcW, part);
  fc_combine_kernel<<<dim3(125, 64), 256, 0, stream>>>(part, fcb, out);
}

// Round 6
// 356.420 us; speedup vs baseline: 1.0030x; 1.0030x over previous
//
#include <hip/hip_runtime.h>
#include <math.h>

#define VOCAB 32000
#define EMBED 512
#define HID   1024
#define BATCH 64
#define SEQ   512

// d_out layout (floats): pred[64*32000]=0 .. 2048000 ; h1 @2048000 ; c1 @2113536 ; attn @2179072
#define OUT_H1   2048000
#define OUT_C1   2113536
#define OUT_ATTN 2179072

typedef __bf16 bf16x8 __attribute__((ext_vector_type(8)));
typedef float  f32x4  __attribute__((ext_vector_type(4)));

__device__ __forceinline__ unsigned short f2bf(float f) {
  unsigned int u = __builtin_bit_cast(unsigned int, f);
  u += 0x7fffu + ((u >> 16) & 1u);   // round-to-nearest-even
  return (unsigned short)(u >> 16);
}
__device__ __forceinline__ float bf2f(unsigned int u) {
  return __builtin_bit_cast(float, u << 16);
}

// async 16B/lane global->LDS; lds ptr must be wave-uniform (HW: base + lane*16)
__device__ __forceinline__ void gload16(const unsigned short* g, unsigned short* l) {
  __builtin_amdgcn_global_load_lds(
      (const __attribute__((address_space(1))) void*)g,
      (__attribute__((address_space(3))) void*)l, 16, 0, 0);
}

// 16 f32 -> 16 bf16 (RNE bit-trick), 32B to LDS
__device__ __forceinline__ void stage16(const float* __restrict__ src, unsigned short* dst) {
  float4 f0 = *(const float4*)(src + 0);
  float4 f1 = *(const float4*)(src + 4);
  float4 f2 = *(const float4*)(src + 8);
  float4 f3 = *(const float4*)(src + 12);
  union { unsigned short us[16]; uint4 u4[2]; } p;
  p.us[0]=f2bf(f0.x);  p.us[1]=f2bf(f0.y);  p.us[2]=f2bf(f0.z);  p.us[3]=f2bf(f0.w);
  p.us[4]=f2bf(f1.x);  p.us[5]=f2bf(f1.y);  p.us[6]=f2bf(f1.z);  p.us[7]=f2bf(f1.w);
  p.us[8]=f2bf(f2.x);  p.us[9]=f2bf(f2.y);  p.us[10]=f2bf(f2.z); p.us[11]=f2bf(f2.w);
  p.us[12]=f2bf(f3.x); p.us[13]=f2bf(f3.y); p.us[14]=f2bf(f3.z); p.us[15]=f2bf(f3.w);
  *(uint4*)(dst + 0) = p.u4[0];
  *(uint4*)(dst + 8) = p.u4[1];
}

// ---- zero workspace (scores+ctx+gates = 360448 floats) — replaces the
// pathologically slow runtime fillBufferAligned small-fill path (152 µs @ 9.5 GB/s)
__global__ void zero_ws_kernel(float* __restrict__ p) {
  int i = blockIdx.x * 256 + threadIdx.x;     // 352*256 threads * 4 floats = 360448
  *(float4*)(p + (size_t)i * 4) = (float4){0.f, 0.f, 0.f, 0.f};
}

// ------------- f32 -> bf16 bulk convert (grid-stride, 8 elems/thread/iter) -------------
__global__ void f2bf_kernel(const float* __restrict__ src, unsigned short* __restrict__ dst,
                            int n8) {
  int i = blockIdx.x * blockDim.x + threadIdx.x;
  int stride = gridDim.x * blockDim.x;
  for (; i < n8; i += stride) {
    const float* s = src + (size_t)i * 8;
    float4 f0 = *(const float4*)s;
    float4 f1 = *(const float4*)(s + 4);
    union { unsigned short us[8]; uint4 u; } p;
    p.us[0]=f2bf(f0.x); p.us[1]=f2bf(f0.y); p.us[2]=f2bf(f0.z); p.us[3]=f2bf(f0.w);
    p.us[4]=f2bf(f1.x); p.us[5]=f2bf(f1.y); p.us[6]=f2bf(f1.z); p.us[7]=f2bf(f1.w);
    *(uint4*)(dst + (size_t)i * 8) = p.u;
  }
}

// ---------------- dh = h0 @ W1^T  (64x1024, K=1024) ----------------
__global__ void dh_kernel(const float* __restrict__ h0, const float* __restrict__ W1,
                          float* __restrict__ dh) {
  __shared__ float hs[HID];
  int b = blockIdx.y, t = threadIdx.x;
  for (int i = t; i < HID; i += 256) hs[i] = h0[b * HID + i];
  __syncthreads();
  int k = blockIdx.x * 256 + t;
  const float* w = W1 + (size_t)k * HID;
  float acc = 0.f;
  for (int hh = 0; hh < HID; hh += 4) {
    float4 wv = *(const float4*)(w + hh);
    float4 hv = *(const float4*)(hs + hh);
    acc += wv.x * hv.x + wv.y * hv.y + wv.z * hv.z + wv.w * hv.w;
  }
  dh[b * HID + k] = acc;
}

// ==== scores: 256x256 tile, BK=64, 8 waves, counted-vmcnt pipeline (r3 schedule) ====
// eh = enc@W2^T fused with  scores += sum_n v[n]*tanh(dh[b,n]+eh)  (atomicAdd)
// LDS swizzle: byte ^= ((byte>>8)&3)<<4 (1KB-stripe involution), applied via
// pre-swizzled GLOBAL source (gload_lds writes linearly) + swizzled ds_read.
__launch_bounds__(512, 2)
__global__ void scores8_kernel(const unsigned short* __restrict__ encb,
                               const unsigned short* __restrict__ W2b,
                               const float* __restrict__ dh, const float* __restrict__ v,
                               float* __restrict__ scores) {
  __shared__ __align__(16) unsigned short sA[2][16384];  // [dbuf][256 rows * 64 k]
  __shared__ __align__(16) unsigned short sB[2][16384];
  __shared__ float dh_s[256];
  __shared__ float v_s[256];

  // bijective XCD-chunked swizzle: 512 wgs, 64/XCD; one m-panel's 4 n-tiles
  // are consecutive on one XCD -> A-panel L2-resident.
  int bid = blockIdx.x;
  int wg = (bid & 7) * 64 + (bid >> 3);
  int mt = wg >> 2, nt = wg & 3;
  int m0 = mt * 256, n0 = nt * 256;

  int t = threadIdx.x;
  int wid = t >> 6, l = t & 63;
  int wr = wid >> 2, wc = wid & 3;     // 2 M-waves x 4 N-waves
  int fr = l & 15, co = (l >> 4) * 8;

  // Stage-source: chunk c covers rows [c*64, c*64+64). Swizzle bits (8,9) come
  // entirely from the intra-chunk byte offset, so chunk sources differ by the
  // uniform constant c*64*HID elements.
  const unsigned short* pa0;
  const unsigned short* pb0;
  int do0 = wid * 512;  // LDS elem offset of this wave's 1KB slice in chunk 0
  {
    int base = wid * 1024 + l * 16;                 // byte offset in chunk 0
    int srel = base ^ (((base >> 8) & 3) << 4);     // involution
    int row = srel >> 7, colE = (srel >> 1) & 63;
    pa0 = encb + (size_t)(m0 + row) * HID + colE;
    pb0 = W2b + (size_t)(n0 + row) * HID + colE;
  }

  f32x4 acc[8][4];
#pragma unroll
  for (int i = 0; i < 8; i++)
#pragma unroll
    for (int j = 0; j < 4; j++) acc[i][j] = (f32x4){0.f, 0.f, 0.f, 0.f};

#define SC_STAGE(T, d)                                                         \
  do {                                                                         \
    int k0_ = (T) * 64;                                                        \
    gload16(pa0 + k0_,          &sA[d][do0]);                                  \
    gload16(pa0 + 65536 + k0_,  &sA[d][do0 + 4096]);                           \
    gload16(pa0 + 131072 + k0_, &sA[d][do0 + 8192]);                           \
    gload16(pa0 + 196608 + k0_, &sA[d][do0 + 12288]);                          \
    gload16(pb0 + k0_,          &sB[d][do0]);                                  \
    gload16(pb0 + 65536 + k0_,  &sB[d][do0 + 4096]);                           \
    gload16(pb0 + 131072 + k0_, &sB[d][do0 + 8192]);                           \
    gload16(pb0 + 196608 + k0_, &sB[d][do0 + 12288]);                          \
  } while (0)

  SC_STAGE(0, 0);
  SC_STAGE(1, 1);

  // swizzled ds_read: elem col ^= ((row>>1)&3)<<3
#define LDF(Mat, row, ks) \
  (*(const bf16x8*)&Mat[(row) * 64 + (((ks) * 32 + co) ^ ((((row) >> 1) & 3) << 3))])

  for (int T = 0; T < 16; ++T) {
    int d = T & 1;
    if (T == 15) asm volatile("s_waitcnt vmcnt(0)" ::: "memory");
    else         asm volatile("s_waitcnt vmcnt(8)" ::: "memory");
    asm volatile("s_barrier" ::: "memory");
    const unsigned short* A = sA[d];
    const unsigned short* B = sB[d];
    bf16x8 a[4][2], b[4][2];
#pragma unroll
    for (int jj = 0; jj < 4; ++jj)
#pragma unroll
      for (int ks = 0; ks < 2; ++ks)
        b[jj][ks] = LDF(B, wc * 64 + jj * 16 + fr, ks);
#pragma unroll
    for (int ii = 0; ii < 4; ++ii)
#pragma unroll
      for (int ks = 0; ks < 2; ++ks)
        a[ii][ks] = LDF(A, wr * 128 + ii * 16 + fr, ks);
    // P0: mq0 x nq0
    __builtin_amdgcn_s_setprio(1);
#pragma unroll
    for (int ii = 0; ii < 4; ++ii)
#pragma unroll
      for (int jj = 0; jj < 2; ++jj)
#pragma unroll
        for (int ks = 0; ks < 2; ++ks)
          acc[ii][jj] = __builtin_amdgcn_mfma_f32_16x16x32_bf16(a[ii][ks], b[jj][ks], acc[ii][jj], 0, 0, 0);
    __builtin_amdgcn_s_setprio(0);
    // P1: mq0 x nq1
    __builtin_amdgcn_s_setprio(1);
#pragma unroll
    for (int ii = 0; ii < 4; ++ii)
#pragma unroll
      for (int jj = 2; jj < 4; ++jj)
#pragma unroll
        for (int ks = 0; ks < 2; ++ks)
          acc[ii][jj] = __builtin_amdgcn_mfma_f32_16x16x32_bf16(a[ii][ks], b[jj][ks], acc[ii][jj], 0, 0, 0);
    __builtin_amdgcn_s_setprio(0);
    // reload A fragments for mq1 (after last mq0 use)
#pragma unroll
    for (int ii = 0; ii < 4; ++ii)
#pragma unroll
      for (int ks = 0; ks < 2; ++ks)
        a[ii][ks] = LDF(A, wr * 128 + 64 + ii * 16 + fr, ks);
    // P2: mq1 x nq1
    __builtin_amdgcn_s_setprio(1);
#pragma unroll
    for (int ii = 0; ii < 4; ++ii)
#pragma unroll
      for (int jj = 2; jj < 4; ++jj)
#pragma unroll
        for (int ks = 0; ks < 2; ++ks)
          acc[4 + ii][jj] = __builtin_amdgcn_mfma_f32_16x16x32_bf16(a[ii][ks], b[jj][ks], acc[4 + ii][jj], 0, 0, 0);
    __builtin_amdgcn_s_setprio(0);
    // P3: mq1 x nq0
    __builtin_amdgcn_s_setprio(1);
#pragma unroll
    for (int ii = 0; ii < 4; ++ii)
#pragma unroll
      for (int jj = 0; jj < 2; ++jj)
#pragma unroll
        for (int ks = 0; ks < 2; ++ks)
          acc[4 + ii][jj] = __builtin_amdgcn_mfma_f32_16x16x32_bf16(a[ii][ks], b[jj][ks], acc[4 + ii][jj], 0, 0, 0);
    __builtin_amdgcn_s_setprio(0);
    asm volatile("s_barrier" ::: "memory");   // all reads of dbuf d done
    if (T < 14) SC_STAGE(T + 2, d);           // prefetch tile T+2 into dbuf d
  }
#undef LDF
#undef SC_STAGE

  // epilogue: partial scores over this 256-wide n-tile
  int b = m0 >> 9;  // 256 | 512 so tile lies in one batch row
  if (t < 256) { dh_s[t] = dh[b * HID + n0 + t]; v_s[t] = v[n0 + t]; }
  __syncthreads();
  float sp[32];
#pragma unroll
  for (int q = 0; q < 32; ++q) sp[q] = 0.f;
#pragma unroll
  for (int ii = 0; ii < 8; ++ii)
#pragma unroll
    for (int jj = 0; jj < 4; ++jj) {
      int nl = wc * 64 + jj * 16 + fr;
      float dv = dh_s[nl], vv = v_s[nl];
#pragma unroll
      for (int r = 0; r < 4; ++r)
        sp[ii * 4 + r] += tanhf(dv + acc[ii][jj][r]) * vv;
    }
#pragma unroll
  for (int q = 0; q < 32; ++q) {
    float x = sp[q];
    x += __shfl_xor(x, 1);
    x += __shfl_xor(x, 2);
    x += __shfl_xor(x, 4);
    x += __shfl_xor(x, 8);
    sp[q] = x;
  }
  if (fr == 0) {
    int rbase = m0 + wr * 128 + (l >> 4) * 4;
#pragma unroll
    for (int ii = 0; ii < 8; ++ii)
#pragma unroll
      for (int r = 0; r < 4; ++r)
        atomicAdd(&scores[rbase + ii * 16 + r], sp[ii * 4 + r]);
  }
}

// ---------------- softmax over S per batch row ----------------
__global__ void softmax_kernel(const float* __restrict__ scores, float* __restrict__ attn) {
  __shared__ float red[8];
  int b = blockIdx.x, t = threadIdx.x;  // 512 threads
  float x = scores[b * SEQ + t];
  float m = x;
  for (int d = 1; d < 64; d <<= 1) m = fmaxf(m, __shfl_xor(m, d));
  if ((t & 63) == 0) red[t >> 6] = m;
  __syncthreads();
  float bm = red[0];
#pragma unroll
  for (int i = 1; i < 8; i++) bm = fmaxf(bm, red[i]);
  float e = expf(x - bm);
  float s = e;
  for (int d = 1; d < 64; d <<= 1) s += __shfl_xor(s, d);
  __syncthreads();
  if ((t & 63) == 0) red[t >> 6] = s;
  __syncthreads();
  float bs = 0.f;
#pragma unroll
  for (int i = 0; i < 8; i++) bs += red[i];
  attn[b * SEQ + t] = e / bs;
}

// ------- context: bf16 enc, 16B/lane; ctx[b,h] = sum_s attn[b,s]*enc[b,s,h] -------
__global__ void context2_kernel(const unsigned short* __restrict__ encb,
                                const float* __restrict__ attn, float* __restrict__ ctx) {
  __shared__ float a_s[64];
  int b = blockIdx.y, s0 = blockIdx.x * 64, t = threadIdx.x;
  if (t < 64) a_s[t] = attn[b * SEQ + s0 + t];
  __syncthreads();
  int hg = (t & 127) * 8, sg = (t >> 7) * 32;  // 128 h-threads x 2 s-groups
  float a0 = 0.f, a1 = 0.f, a2 = 0.f, a3 = 0.f, a4 = 0.f, a5 = 0.f, a6 = 0.f, a7 = 0.f;
  const unsigned short* base = encb + ((size_t)b * SEQ + s0 + sg) * HID + hg;
  for (int s = 0; s < 32; s++) {
    uint4 ev = *(const uint4*)(base + (size_t)s * HID);
    float a = a_s[sg + s];
    a0 += a * bf2f(ev.x & 0xffffu); a1 += a * bf2f(ev.x >> 16);
    a2 += a * bf2f(ev.y & 0xffffu); a3 += a * bf2f(ev.y >> 16);
    a4 += a * bf2f(ev.z & 0xffffu); a5 += a * bf2f(ev.z >> 16);
    a6 += a * bf2f(ev.w & 0xffffu); a7 += a * bf2f(ev.w >> 16);
  }
  atomicAdd(&ctx[b * HID + hg + 0], a0);
  atomicAdd(&ctx[b * HID + hg + 1], a1);
  atomicAdd(&ctx[b * HID + hg + 2], a2);
  atomicAdd(&ctx[b * HID + hg + 3], a3);
  atomicAdd(&ctx[b * HID + hg + 4], a4);
  atomicAdd(&ctx[b * HID + hg + 5], a5);
  atomicAdd(&ctx[b * HID + hg + 6], a6);
  atomicAdd(&ctx[b * HID + hg + 7], a7);
}

// ---- gates (xcat fused): gates[b,j] += x[b,:]·[W_ih|W_hh][j,:], K-split 8 ----
// x = [emb[tok[b]] (512) | ctx[b] (1024) | h0[b] (1024)]
__launch_bounds__(256)
__global__ void gates_kernel(const int* __restrict__ tok, const float* __restrict__ emb,
                             const float* __restrict__ ctx, const float* __restrict__ h0,
                             const float* __restrict__ W_ih, const float* __restrict__ W_hh,
                             float* __restrict__ gates) {
  __shared__ float xk[64 * 33];
  __shared__ float wk[64 * 33];
  int j0 = blockIdx.x * 64, kz = blockIdx.y, t = threadIdx.x;
  int b0 = (t >> 6) * 16, jj = t & 63;
  int rowX = t >> 2, qk = (t & 3) * 8;
  int tk = tok[rowX];
  float acc[16];
#pragma unroll
  for (int i = 0; i < 16; i++) acc[i] = 0.f;
  for (int ks = 0; ks < 10; ks++) {
    int k0 = kz * 320 + ks * 32;
    __syncthreads();
    {
      int kg = k0 + qk;  // 8-elem segment never crosses 512/1536
      const float* src;
      if (kg < 512)        src = emb + (size_t)tk * EMBED + kg;
      else if (kg < 1536)  src = ctx + rowX * HID + (kg - 512);
      else                 src = h0 + rowX * HID + (kg - 1536);
#pragma unroll
      for (int i = 0; i < 8; i++) xk[rowX * 33 + qk + i] = src[i];
    }
    {
      int j = j0 + rowX;
      int kg = k0 + qk;
      const float* src = (kg < 1536) ? (W_ih + (size_t)j * 1536 + kg)
                                     : (W_hh + (size_t)j * 1024 + (kg - 1536));
#pragma unroll
      for (int i = 0; i < 8; i++) wk[rowX * 33 + qk + i] = src[i];
    }
    __syncthreads();
#pragma unroll
    for (int kk = 0; kk < 32; kk++) {
      float wv = wk[jj * 33 + kk];
#pragma unroll
      for (int bb = 0; bb < 16; bb++) acc[bb] += xk[(b0 + bb) * 33 + kk] * wv;
    }
  }
#pragma unroll
  for (int bb = 0; bb < 16; bb++)
    atomicAdd(&gates[(size_t)(b0 + bb) * 4096 + j0 + jj], acc[bb]);
}

// ---------------- LSTM pointwise -> h1, c1 ----------------
__global__ void lstm_kernel(const float* __restrict__ gates, const float* __restrict__ b_ih,
                            const float* __restrict__ b_hh, const float* __restrict__ c0,
                            float* __restrict__ out) {
  int b = blockIdx.y;
  int hh = blockIdx.x * 256 + threadIdx.x;
  const float* g = gates + (size_t)b * 4096;
  float gi = g[hh]        + b_ih[hh]        + b_hh[hh];
  float gf = g[1024 + hh] + b_ih[1024 + hh] + b_hh[1024 + hh];
  float gg = g[2048 + hh] + b_ih[2048 + hh] + b_hh[2048 + hh];
  float go = g[3072 + hh] + b_ih[3072 + hh] + b_hh[3072 + hh];
  float si = 1.f / (1.f + expf(-gi));
  float sf = 1.f / (1.f + expf(-gf));
  float so = 1.f / (1.f + expf(-go));
  float c1 = sf * c0[b * HID + hh] + si * tanhf(gg);
  float h1 = so * tanhf(c1);
  out[OUT_H1 + b * HID + hh] = h1;
  out[OUT_C1 + b * HID + hh] = c1;
}

// ---- fc: K-split x4, partial planes (no atomics) ----
// part[kq] = A_kq @ fc_W[:, kq*512:+512]^T   (M=64, N=32000, K=512 each)
__launch_bounds__(256)
__global__ void fc4p_kernel(const float* __restrict__ h1, const float* __restrict__ ctx,
                            const float* __restrict__ fcW, float* __restrict__ part) {
  __shared__ __align__(16) unsigned short lA[64 * 40];
  __shared__ __align__(16) unsigned short lB[128 * 40];
  int n0 = blockIdx.x * 128, kq = blockIdx.y;      // kq: K quarter (512 wide)
  const float* A = (kq < 2) ? h1 : ctx;
  int aoff = (kq & 1) * 512;
  int t = threadIdx.x, w = t >> 6, l = t & 63;
  f32x4 acc[4][2];
#pragma unroll
  for (int i = 0; i < 4; i++)
#pragma unroll
    for (int j = 0; j < 2; j++) acc[i][j] = (f32x4){0.f, 0.f, 0.f, 0.f};
  int rowA = t >> 2, qA = (t & 3) * 8;   // 64 rows x 4 quads of 8
  int rowB = t >> 1, hB = t & 1;         // 128 rows x 2 halves of 16

  for (int kt = 0; kt < 16; kt++) {
    int k0 = kt * 32;
    {  // A stage: 8 floats -> 8 bf16 (RNE bit-trick)
      const float* src = A + rowA * HID + aoff + k0 + qA;
      float4 f0 = *(const float4*)src;
      float4 f1 = *(const float4*)(src + 4);
      union { unsigned short us[8]; uint4 u; } p;
      p.us[0]=f2bf(f0.x); p.us[1]=f2bf(f0.y); p.us[2]=f2bf(f0.z); p.us[3]=f2bf(f0.w);
      p.us[4]=f2bf(f1.x); p.us[5]=f2bf(f1.y); p.us[6]=f2bf(f1.z); p.us[7]=f2bf(f1.w);
      *(uint4*)&lA[rowA * 40 + qA] = p.u;
    }
    stage16(fcW + (size_t)(n0 + rowB) * 2048 + kq * 512 + k0 + hB * 16,
            &lB[rowB * 40 + hB * 16]);
    __syncthreads();
    bf16x8 af[4], bv[2];
    int co = (l >> 4) * 8;
#pragma unroll
    for (int i = 0; i < 4; i++) af[i] = *(const bf16x8*)&lA[(i * 16 + (l & 15)) * 40 + co];
#pragma unroll
    for (int j = 0; j < 2; j++) bv[j] = *(const bf16x8*)&lB[(w * 32 + j * 16 + (l & 15)) * 40 + co];
#pragma unroll
    for (int i = 0; i < 4; i++)
#pragma unroll
      for (int j = 0; j < 2; j++)
        acc[i][j] = __builtin_amdgcn_mfma_f32_16x16x32_bf16(af[i], bv[j], acc[i][j], 0, 0, 0);
    __syncthreads();
  }
#pragma unroll
  for (int i = 0; i < 4; i++)
#pragma unroll
    for (int j = 0; j < 2; j++) {
      int n = n0 + w * 32 + j * 16 + (l & 15);
#pragma unroll
      for (int r = 0; r < 4; r++) {
        int m = i * 16 + (l >> 4) * 4 + r;
        part[(size_t)kq * 2048000 + (size_t)m * VOCAB + n] = acc[i][j][r];
      }
    }
}

__global__ void fc_combine_kernel(const float* __restrict__ part,
                                  const float* __restrict__ fcb, float* __restrict__ pred) {
  int n = blockIdx.x * 256 + threadIdx.x;   // 125*256 = 32000
  int m = blockIdx.y;
  size_t i = (size_t)m * VOCAB + n;
  pred[i] = part[i] + part[2048000 + i] + part[4096000 + i] + part[6144000 + i] + fcb[n];
}

extern "C" void kernel_launch(void* const* d_in, const int* in_sizes, int n_in,
                              void* d_out, int out_size, void* d_ws, size_t ws_size,
                              hipStream_t stream) {
  const int*   tok  = (const int*)d_in[0];
  const float* h    = (const float*)d_in[1];
  const float* c    = (const float*)d_in[2];
  const float* enc  = (const float*)d_in[3];
  const float* emb  = (const float*)d_in[4];
  const float* W1   = (const float*)d_in[5];
  const float* W2   = (const float*)d_in[6];
  const float* v    = (const float*)d_in[7];
  const float* W_ih = (const float*)d_in[8];
  const float* W_hh = (const float*)d_in[9];
  const float* b_ih = (const float*)d_in[10];
  const float* b_hh = (const float*)d_in[11];
  const float* fcW  = (const float*)d_in[12];
  const float* fcb  = (const float*)d_in[13];
  float* out = (float*)d_out;

  float* wsf    = (float*)d_ws;
  float* scores = wsf;             // 32768
  float* ctx    = wsf + 32768;     // 65536
  float* gates  = wsf + 98304;     // 262144
  float* dh     = wsf + 360448;    // 65536
  float* part   = wsf + 425984;    // 4*2048000
  unsigned short* encb = (unsigned short*)(wsf + 8617984);   // 33,554,432 bf16
  unsigned short* W2b  = encb + (size_t)BATCH * SEQ * HID;   //  1,048,576 bf16

  // zero scores+ctx+gates via our own kernel (runtime small-fill path is ~152 µs!)
  zero_ws_kernel<<<352, 256, 0, stream>>>(wsf);

  f2bf_kernel<<<2048, 256, 0, stream>>>(enc, encb, BATCH * SEQ * HID / 8);
  f2bf_kernel<<<512, 256, 0, stream>>>(W2, W2b, HID * HID / 8);
  dh_kernel<<<dim3(4, 64), 256, 0, stream>>>(h, W1, dh);
  scores8_kernel<<<512, 512, 0, stream>>>(encb, W2b, dh, v, scores);
  softmax_kernel<<<64, 512, 0, stream>>>(scores, out + OUT_ATTN);
  context2_kernel<<<dim3(8, 64), 256, 0, stream>>>(encb, out + OUT_ATTN, ctx);
  gates_kernel<<<dim3(64, 8), 256, 0, stream>>>(tok, emb, ctx, h, W_ih, W_hh, gates);
  lstm_kernel<<<dim3(4, 64), 256, 0, stream>>>(gates, b_ih, b_hh, c, out);
  fc4p_kernel<<<dim3(250, 4), 256, 0, stream>>>(out + OUT_H1, ctx, fcW, part);
  fc_combine_kernel<<<dim3(125, 64), 256, 0, stream>>>(part, fcb, out);
}

// Round 7
// 292.172 us; speedup vs baseline: 1.2236x; 1.2199x over previous
//
#include <hip/hip_runtime.h>
#include <math.h>

#define VOCAB 32000
#define EMBED 512
#define HID   1024
#define BATCH 64
#define SEQ   512

// d_out layout (floats): pred[64*32000]=0 .. 2048000 ; h1 @2048000 ; c1 @2113536 ; attn @2179072
#define OUT_H1   2048000
#define OUT_C1   2113536
#define OUT_ATTN 2179072

typedef __bf16 bf16x8 __attribute__((ext_vector_type(8)));
typedef float  f32x4  __attribute__((ext_vector_type(4)));

__device__ __forceinline__ unsigned short f2bf(float f) {
  unsigned int u = __builtin_bit_cast(unsigned int, f);
  u += 0x7fffu + ((u >> 16) & 1u);   // round-to-nearest-even
  return (unsigned short)(u >> 16);
}
__device__ __forceinline__ float bf2f(unsigned int u) {
  return __builtin_bit_cast(float, u << 16);
}

// fast tanh: (e^{2x}-1)/(e^{2x}+1) via hw exp2; clamp avoids inf/inf
__device__ __forceinline__ float fast_tanh(float x) {
  float cx = fminf(fmaxf(x, -15.f), 15.f);
  float t = __builtin_amdgcn_exp2f(cx * 2.8853900817779268f);  // e^{2x}
  return (t - 1.f) / (t + 1.f);
}

// async 16B/lane global->LDS; lds ptr must be wave-uniform (HW: base + lane*16)
__device__ __forceinline__ void gload16(const unsigned short* g, unsigned short* l) {
  __builtin_amdgcn_global_load_lds(
      (const __attribute__((address_space(1))) void*)g,
      (__attribute__((address_space(3))) void*)l, 16, 0, 0);
}

// 16 f32 -> 16 bf16 (RNE bit-trick), 32B to LDS
__device__ __forceinline__ void stage16(const float* __restrict__ src, unsigned short* dst) {
  float4 f0 = *(const float4*)(src + 0);
  float4 f1 = *(const float4*)(src + 4);
  float4 f2 = *(const float4*)(src + 8);
  float4 f3 = *(const float4*)(src + 12);
  union { unsigned short us[16]; uint4 u4[2]; } p;
  p.us[0]=f2bf(f0.x);  p.us[1]=f2bf(f0.y);  p.us[2]=f2bf(f0.z);  p.us[3]=f2bf(f0.w);
  p.us[4]=f2bf(f1.x);  p.us[5]=f2bf(f1.y);  p.us[6]=f2bf(f1.z);  p.us[7]=f2bf(f1.w);
  p.us[8]=f2bf(f2.x);  p.us[9]=f2bf(f2.y);  p.us[10]=f2bf(f2.z); p.us[11]=f2bf(f2.w);
  p.us[12]=f2bf(f3.x); p.us[13]=f2bf(f3.y); p.us[14]=f2bf(f3.z); p.us[15]=f2bf(f3.w);
  *(uint4*)(dst + 0) = p.u4[0];
  *(uint4*)(dst + 8) = p.u4[1];
}

// ---- zero scores+ctx (atomic targets): 98304 floats ----
__global__ void zero_ws_kernel(float* __restrict__ p) {
  int i = blockIdx.x * 256 + threadIdx.x;     // 96*256 threads * 4 floats = 98304
  *(float4*)(p + (size_t)i * 4) = (float4){0.f, 0.f, 0.f, 0.f};
}

// ------------- f32 -> bf16 bulk convert (grid-stride, 8 elems/thread/iter) -------------
__global__ void f2bf_kernel(const float* __restrict__ src, unsigned short* __restrict__ dst,
                            int n8) {
  int i = blockIdx.x * blockDim.x + threadIdx.x;
  int stride = gridDim.x * blockDim.x;
  for (; i < n8; i += stride) {
    const float* s = src + (size_t)i * 8;
    float4 f0 = *(const float4*)s;
    float4 f1 = *(const float4*)(s + 4);
    union { unsigned short us[8]; uint4 u; } p;
    p.us[0]=f2bf(f0.x); p.us[1]=f2bf(f0.y); p.us[2]=f2bf(f0.z); p.us[3]=f2bf(f0.w);
    p.us[4]=f2bf(f1.x); p.us[5]=f2bf(f1.y); p.us[6]=f2bf(f1.z); p.us[7]=f2bf(f1.w);
    *(uint4*)(dst + (size_t)i * 8) = p.u;
  }
}

// ---------------- dh = h0 @ W1^T  (64x1024, K=1024) ----------------
__global__ void dh_kernel(const float* __restrict__ h0, const float* __restrict__ W1,
                          float* __restrict__ dh) {
  __shared__ float hs[HID];
  int b = blockIdx.y, t = threadIdx.x;
  for (int i = t; i < HID; i += 256) hs[i] = h0[b * HID + i];
  __syncthreads();
  int k = blockIdx.x * 256 + t;
  const float* w = W1 + (size_t)k * HID;
  float acc = 0.f;
  for (int hh = 0; hh < HID; hh += 4) {
    float4 wv = *(const float4*)(w + hh);
    float4 hv = *(const float4*)(hs + hh);
    acc += wv.x * hv.x + wv.y * hv.y + wv.z * hv.z + wv.w * hv.w;
  }
  dh[b * HID + k] = acc;
}

// ==== scores: 256x256 tile, BK=64, 8 waves, counted-vmcnt pipeline ====
__launch_bounds__(512, 2)
__global__ void scores8_kernel(const unsigned short* __restrict__ encb,
                               const unsigned short* __restrict__ W2b,
                               const float* __restrict__ dh, const float* __restrict__ v,
                               float* __restrict__ scores) {
  __shared__ __align__(16) unsigned short sA[2][16384];  // [dbuf][256 rows * 64 k]
  __shared__ __align__(16) unsigned short sB[2][16384];
  __shared__ float dh_s[256];
  __shared__ float v_s[256];

  int bid = blockIdx.x;
  int wg = (bid & 7) * 64 + (bid >> 3);
  int mt = wg >> 2, nt = wg & 3;
  int m0 = mt * 256, n0 = nt * 256;

  int t = threadIdx.x;
  int wid = t >> 6, l = t & 63;
  int wr = wid >> 2, wc = wid & 3;     // 2 M-waves x 4 N-waves
  int fr = l & 15, co = (l >> 4) * 8;

  const unsigned short* pa0;
  const unsigned short* pb0;
  int do0 = wid * 512;
  {
    int base = wid * 1024 + l * 16;                 // byte offset in chunk 0
    int srel = base ^ (((base >> 8) & 3) << 4);     // involution
    int row = srel >> 7, colE = (srel >> 1) & 63;
    pa0 = encb + (size_t)(m0 + row) * HID + colE;
    pb0 = W2b + (size_t)(n0 + row) * HID + colE;
  }

  f32x4 acc[8][4];
#pragma unroll
  for (int i = 0; i < 8; i++)
#pragma unroll
    for (int j = 0; j < 4; j++) acc[i][j] = (f32x4){0.f, 0.f, 0.f, 0.f};

#define SC_STAGE(T, d)                                                         \
  do {                                                                         \
    int k0_ = (T) * 64;                                                        \
    gload16(pa0 + k0_,          &sA[d][do0]);                                  \
    gload16(pa0 + 65536 + k0_,  &sA[d][do0 + 4096]);                           \
    gload16(pa0 + 131072 + k0_, &sA[d][do0 + 8192]);                           \
    gload16(pa0 + 196608 + k0_, &sA[d][do0 + 12288]);                          \
    gload16(pb0 + k0_,          &sB[d][do0]);                                  \
    gload16(pb0 + 65536 + k0_,  &sB[d][do0 + 4096]);                           \
    gload16(pb0 + 131072 + k0_, &sB[d][do0 + 8192]);                           \
    gload16(pb0 + 196608 + k0_, &sB[d][do0 + 12288]);                          \
  } while (0)

  SC_STAGE(0, 0);
  SC_STAGE(1, 1);

#define LDF(Mat, row, ks) \
  (*(const bf16x8*)&Mat[(row) * 64 + (((ks) * 32 + co) ^ ((((row) >> 1) & 3) << 3))])

  for (int T = 0; T < 16; ++T) {
    int d = T & 1;
    if (T == 15) asm volatile("s_waitcnt vmcnt(0)" ::: "memory");
    else         asm volatile("s_waitcnt vmcnt(8)" ::: "memory");
    asm volatile("s_barrier" ::: "memory");
    const unsigned short* A = sA[d];
    const unsigned short* B = sB[d];
    bf16x8 a[4][2], b[4][2];
#pragma unroll
    for (int jj = 0; jj < 4; ++jj)
#pragma unroll
      for (int ks = 0; ks < 2; ++ks)
        b[jj][ks] = LDF(B, wc * 64 + jj * 16 + fr, ks);
#pragma unroll
    for (int ii = 0; ii < 4; ++ii)
#pragma unroll
      for (int ks = 0; ks < 2; ++ks)
        a[ii][ks] = LDF(A, wr * 128 + ii * 16 + fr, ks);
    __builtin_amdgcn_s_setprio(1);
#pragma unroll
    for (int ii = 0; ii < 4; ++ii)
#pragma unroll
      for (int jj = 0; jj < 2; ++jj)
#pragma unroll
        for (int ks = 0; ks < 2; ++ks)
          acc[ii][jj] = __builtin_amdgcn_mfma_f32_16x16x32_bf16(a[ii][ks], b[jj][ks], acc[ii][jj], 0, 0, 0);
    __builtin_amdgcn_s_setprio(0);
    __builtin_amdgcn_s_setprio(1);
#pragma unroll
    for (int ii = 0; ii < 4; ++ii)
#pragma unroll
      for (int jj = 2; jj < 4; ++jj)
#pragma unroll
        for (int ks = 0; ks < 2; ++ks)
          acc[ii][jj] = __builtin_amdgcn_mfma_f32_16x16x32_bf16(a[ii][ks], b[jj][ks], acc[ii][jj], 0, 0, 0);
    __builtin_amdgcn_s_setprio(0);
#pragma unroll
    for (int ii = 0; ii < 4; ++ii)
#pragma unroll
      for (int ks = 0; ks < 2; ++ks)
        a[ii][ks] = LDF(A, wr * 128 + 64 + ii * 16 + fr, ks);
    __builtin_amdgcn_s_setprio(1);
#pragma unroll
    for (int ii = 0; ii < 4; ++ii)
#pragma unroll
      for (int jj = 2; jj < 4; ++jj)
#pragma unroll
        for (int ks = 0; ks < 2; ++ks)
          acc[4 + ii][jj] = __builtin_amdgcn_mfma_f32_16x16x32_bf16(a[ii][ks], b[jj][ks], acc[4 + ii][jj], 0, 0, 0);
    __builtin_amdgcn_s_setprio(0);
    __builtin_amdgcn_s_setprio(1);
#pragma unroll
    for (int ii = 0; ii < 4; ++ii)
#pragma unroll
      for (int jj = 0; jj < 2; ++jj)
#pragma unroll
        for (int ks = 0; ks < 2; ++ks)
          acc[4 + ii][jj] = __builtin_amdgcn_mfma_f32_16x16x32_bf16(a[ii][ks], b[jj][ks], acc[4 + ii][jj], 0, 0, 0);
    __builtin_amdgcn_s_setprio(0);
    asm volatile("s_barrier" ::: "memory");   // all reads of dbuf d done
    if (T < 14) SC_STAGE(T + 2, d);           // prefetch tile T+2 into dbuf d
  }
#undef LDF
#undef SC_STAGE

  // epilogue: partial scores over this 256-wide n-tile (fast_tanh)
  int b = m0 >> 9;
  if (t < 256) { dh_s[t] = dh[b * HID + n0 + t]; v_s[t] = v[n0 + t]; }
  __syncthreads();
  float sp[32];
#pragma unroll
  for (int q = 0; q < 32; ++q) sp[q] = 0.f;
#pragma unroll
  for (int ii = 0; ii < 8; ++ii)
#pragma unroll
    for (int jj = 0; jj < 4; ++jj) {
      int nl = wc * 64 + jj * 16 + fr;
      float dv = dh_s[nl], vv = v_s[nl];
#pragma unroll
      for (int r = 0; r < 4; ++r)
        sp[ii * 4 + r] += fast_tanh(dv + acc[ii][jj][r]) * vv;
    }
#pragma unroll
  for (int q = 0; q < 32; ++q) {
    float x = sp[q];
    x += __shfl_xor(x, 1);
    x += __shfl_xor(x, 2);
    x += __shfl_xor(x, 4);
    x += __shfl_xor(x, 8);
    sp[q] = x;
  }
  if (fr == 0) {
    int rbase = m0 + wr * 128 + (l >> 4) * 4;
#pragma unroll
    for (int ii = 0; ii < 8; ++ii)
#pragma unroll
      for (int r = 0; r < 4; ++r)
        atomicAdd(&scores[rbase + ii * 16 + r], sp[ii * 4 + r]);
  }
}

// ---------------- softmax over S per batch row ----------------
__global__ void softmax_kernel(const float* __restrict__ scores, float* __restrict__ attn) {
  __shared__ float red[8];
  int b = blockIdx.x, t = threadIdx.x;  // 512 threads
  float x = scores[b * SEQ + t];
  float m = x;
  for (int d = 1; d < 64; d <<= 1) m = fmaxf(m, __shfl_xor(m, d));
  if ((t & 63) == 0) red[t >> 6] = m;
  __syncthreads();
  float bm = red[0];
#pragma unroll
  for (int i = 1; i < 8; i++) bm = fmaxf(bm, red[i]);
  float e = expf(x - bm);
  float s = e;
  for (int d = 1; d < 64; d <<= 1) s += __shfl_xor(s, d);
  __syncthreads();
  if ((t & 63) == 0) red[t >> 6] = s;
  __syncthreads();
  float bs = 0.f;
#pragma unroll
  for (int i = 0; i < 8; i++) bs += red[i];
  attn[b * SEQ + t] = e / bs;
}

// ------- context: bf16 enc, 16B/lane; ctx[b,h] = sum_s attn[b,s]*enc[b,s,h] -------
__global__ void context2_kernel(const unsigned short* __restrict__ encb,
                                const float* __restrict__ attn, float* __restrict__ ctx) {
  __shared__ float a_s[64];
  int b = blockIdx.y, s0 = blockIdx.x * 64, t = threadIdx.x;
  if (t < 64) a_s[t] = attn[b * SEQ + s0 + t];
  __syncthreads();
  int hg = (t & 127) * 8, sg = (t >> 7) * 32;  // 128 h-threads x 2 s-groups
  float a0 = 0.f, a1 = 0.f, a2 = 0.f, a3 = 0.f, a4 = 0.f, a5 = 0.f, a6 = 0.f, a7 = 0.f;
  const unsigned short* base = encb + ((size_t)b * SEQ + s0 + sg) * HID + hg;
  for (int s = 0; s < 32; s++) {
    uint4 ev = *(const uint4*)(base + (size_t)s * HID);
    float a = a_s[sg + s];
    a0 += a * bf2f(ev.x & 0xffffu); a1 += a * bf2f(ev.x >> 16);
    a2 += a * bf2f(ev.y & 0xffffu); a3 += a * bf2f(ev.y >> 16);
    a4 += a * bf2f(ev.z & 0xffffu); a5 += a * bf2f(ev.z >> 16);
    a6 += a * bf2f(ev.w & 0xffffu); a7 += a * bf2f(ev.w >> 16);
  }
  atomicAdd(&ctx[b * HID + hg + 0], a0);
  atomicAdd(&ctx[b * HID + hg + 1], a1);
  atomicAdd(&ctx[b * HID + hg + 2], a2);
  atomicAdd(&ctx[b * HID + hg + 3], a3);
  atomicAdd(&ctx[b * HID + hg + 4], a4);
  atomicAdd(&ctx[b * HID + hg + 5], a5);
  atomicAdd(&ctx[b * HID + hg + 6], a6);
  atomicAdd(&ctx[b * HID + hg + 7], a7);
}

// ==== gates via MFMA: gpart[kz] = x @ W[:, kz*320:+320]^T  (M=64, N=4096) ====
// x = [emb[tok[b]] (512) | ctx[b] (1024) | h0[b] (1024)]; W = [W_ih | W_hh] cols
__launch_bounds__(256)
__global__ void gates8p_kernel(const int* __restrict__ tok, const float* __restrict__ emb,
                               const float* __restrict__ ctx, const float* __restrict__ h0,
                               const float* __restrict__ W_ih, const float* __restrict__ W_hh,
                               float* __restrict__ gpart) {
  __shared__ __align__(16) unsigned short lA[64 * 40];
  __shared__ __align__(16) unsigned short lB[128 * 40];
  int n0 = blockIdx.x * 128, kz = blockIdx.y;   // 32 n-blocks x 8 K-slices
  int kbase = kz * 320;
  int t = threadIdx.x, w = t >> 6, l = t & 63;
  f32x4 acc[4][2];
#pragma unroll
  for (int i = 0; i < 4; i++)
#pragma unroll
    for (int j = 0; j < 2; j++) acc[i][j] = (f32x4){0.f, 0.f, 0.f, 0.f};
  int rowA = t >> 2, qA = (t & 3) * 8;   // 64 rows x 4 quads of 8
  int rowB = t >> 1, hB = t & 1;         // 128 rows x 2 halves of 16
  int tkA = tok[rowA];

  for (int kt = 0; kt < 10; kt++) {
    int k0 = kbase + kt * 32;
    {  // A stage: x[rowA, k0+qA..+8] -> bf16 (segments never cross 512/1536)
      int kg = k0 + qA;
      const float* src;
      if (kg < 512)        src = emb + (size_t)tkA * EMBED + kg;
      else if (kg < 1536)  src = ctx + rowA * HID + (kg - 512);
      else                 src = h0 + rowA * HID + (kg - 1536);
      float4 f0 = *(const float4*)src;
      float4 f1 = *(const float4*)(src + 4);
      union { unsigned short us[8]; uint4 u; } p;
      p.us[0]=f2bf(f0.x); p.us[1]=f2bf(f0.y); p.us[2]=f2bf(f0.z); p.us[3]=f2bf(f0.w);
      p.us[4]=f2bf(f1.x); p.us[5]=f2bf(f1.y); p.us[6]=f2bf(f1.z); p.us[7]=f2bf(f1.w);
      *(uint4*)&lA[rowA * 40 + qA] = p.u;
    }
    {  // B stage: W[n0+rowB, k0+hB*16..+16] (16-seg never crosses 1536)
      int kg = k0 + hB * 16;
      const float* src = (kg < 1536) ? (W_ih + (size_t)(n0 + rowB) * 1536 + kg)
                                     : (W_hh + (size_t)(n0 + rowB) * 1024 + (kg - 1536));
      stage16(src, &lB[rowB * 40 + hB * 16]);
    }
    __syncthreads();
    bf16x8 af[4], bv[2];
    int co = (l >> 4) * 8;
#pragma unroll
    for (int i = 0; i < 4; i++) af[i] = *(const bf16x8*)&lA[(i * 16 + (l & 15)) * 40 + co];
#pragma unroll
    for (int j = 0; j < 2; j++) bv[j] = *(const bf16x8*)&lB[(w * 32 + j * 16 + (l & 15)) * 40 + co];
#pragma unroll
    for (int i = 0; i < 4; i++)
#pragma unroll
      for (int j = 0; j < 2; j++)
        acc[i][j] = __builtin_amdgcn_mfma_f32_16x16x32_bf16(af[i], bv[j], acc[i][j], 0, 0, 0);
    __syncthreads();
  }
#pragma unroll
  for (int i = 0; i < 4; i++)
#pragma unroll
    for (int j = 0; j < 2; j++) {
      int n = n0 + w * 32 + j * 16 + (l & 15);
#pragma unroll
      for (int r = 0; r < 4; r++) {
        int m = i * 16 + (l >> 4) * 4 + r;
        gpart[(size_t)kz * 262144 + (size_t)m * 4096 + n] = acc[i][j][r];
      }
    }
}

// ------- LSTM pointwise (fused 8-plane gate combine) -> h1, c1 -------
__global__ void lstm_kernel(const float* __restrict__ gpart, const float* __restrict__ b_ih,
                            const float* __restrict__ b_hh, const float* __restrict__ c0,
                            float* __restrict__ out) {
  int b = blockIdx.y;
  int hh = blockIdx.x * 256 + threadIdx.x;
  float gi = b_ih[hh]        + b_hh[hh];
  float gf = b_ih[1024 + hh] + b_hh[1024 + hh];
  float gg = b_ih[2048 + hh] + b_hh[2048 + hh];
  float go = b_ih[3072 + hh] + b_hh[3072 + hh];
#pragma unroll
  for (int kz = 0; kz < 8; kz++) {
    const float* g = gpart + (size_t)kz * 262144 + (size_t)b * 4096;
    gi += g[hh];
    gf += g[1024 + hh];
    gg += g[2048 + hh];
    go += g[3072 + hh];
  }
  float si = 1.f / (1.f + expf(-gi));
  float sf = 1.f / (1.f + expf(-gf));
  float so = 1.f / (1.f + expf(-go));
  float c1 = sf * c0[b * HID + hh] + si * tanhf(gg);
  float h1 = so * tanhf(c1);
  out[OUT_H1 + b * HID + hh] = h1;
  out[OUT_C1 + b * HID + hh] = c1;
}

// ---- fc: K-split x2 (r3-proven), partial planes (no atomics) ----
__launch_bounds__(256)
__global__ void fc2p_kernel(const float* __restrict__ h1, const float* __restrict__ ctx,
                            const float* __restrict__ fcW, float* __restrict__ part) {
  __shared__ __align__(16) unsigned short lA[64 * 40];
  __shared__ __align__(16) unsigned short lB[128 * 40];
  int n0 = blockIdx.x * 128, kz = blockIdx.y;
  const float* A = kz ? ctx : h1;
  int t = threadIdx.x, w = t >> 6, l = t & 63;
  f32x4 acc[4][2];
#pragma unroll
  for (int i = 0; i < 4; i++)
#pragma unroll
    for (int j = 0; j < 2; j++) acc[i][j] = (f32x4){0.f, 0.f, 0.f, 0.f};
  int rowA = t >> 2, qA = (t & 3) * 8;
  int rowB = t >> 1, hB = t & 1;

  for (int kt = 0; kt < 32; kt++) {
    int k0 = kt * 32;
    {
      const float* src = A + rowA * HID + k0 + qA;
      float4 f0 = *(const float4*)src;
      float4 f1 = *(const float4*)(src + 4);
      union { unsigned short us[8]; uint4 u; } p;
      p.us[0]=f2bf(f0.x); p.us[1]=f2bf(f0.y); p.us[2]=f2bf(f0.z); p.us[3]=f2bf(f0.w);
      p.us[4]=f2bf(f1.x); p.us[5]=f2bf(f1.y); p.us[6]=f2bf(f1.z); p.us[7]=f2bf(f1.w);
      *(uint4*)&lA[rowA * 40 + qA] = p.u;
    }
    stage16(fcW + (size_t)(n0 + rowB) * 2048 + kz * 1024 + k0 + hB * 16,
            &lB[rowB * 40 + hB * 16]);
    __syncthreads();
    bf16x8 af[4], bv[2];
    int co = (l >> 4) * 8;
#pragma unroll
    for (int i = 0; i < 4; i++) af[i] = *(const bf16x8*)&lA[(i * 16 + (l & 15)) * 40 + co];
#pragma unroll
    for (int j = 0; j < 2; j++) bv[j] = *(const bf16x8*)&lB[(w * 32 + j * 16 + (l & 15)) * 40 + co];
#pragma unroll
    for (int i = 0; i < 4; i++)
#pragma unroll
      for (int j = 0; j < 2; j++)
        acc[i][j] = __builtin_amdgcn_mfma_f32_16x16x32_bf16(af[i], bv[j], acc[i][j], 0, 0, 0);
    __syncthreads();
  }
#pragma unroll
  for (int i = 0; i < 4; i++)
#pragma unroll
    for (int j = 0; j < 2; j++) {
      int n = n0 + w * 32 + j * 16 + (l & 15);
#pragma unroll
      for (int r = 0; r < 4; r++) {
        int m = i * 16 + (l >> 4) * 4 + r;
        part[(size_t)kz * 2048000 + (size_t)m * VOCAB + n] = acc[i][j][r];
      }
    }
}

__global__ void fc_combine_kernel(const float* __restrict__ part,
                                  const float* __restrict__ fcb, float* __restrict__ pred) {
  int n = blockIdx.x * 256 + threadIdx.x;   // 125*256 = 32000
  int m = blockIdx.y;
  size_t i = (size_t)m * VOCAB + n;
  pred[i] = part[i] + part[2048000 + i] + fcb[n];
}

extern "C" void kernel_launch(void* const* d_in, const int* in_sizes, int n_in,
                              void* d_out, int out_size, void* d_ws, size_t ws_size,
                              hipStream_t stream) {
  const int*   tok  = (const int*)d_in[0];
  const float* h    = (const float*)d_in[1];
  const float* c    = (const float*)d_in[2];
  const float* enc  = (const float*)d_in[3];
  const float* emb  = (const float*)d_in[4];
  const float* W1   = (const float*)d_in[5];
  const float* W2   = (const float*)d_in[6];
  const float* v    = (const float*)d_in[7];
  const float* W_ih = (const float*)d_in[8];
  const float* W_hh = (const float*)d_in[9];
  const float* b_ih = (const float*)d_in[10];
  const float* b_hh = (const float*)d_in[11];
  const float* fcW  = (const float*)d_in[12];
  const float* fcb  = (const float*)d_in[13];
  float* out = (float*)d_out;

  float* wsf    = (float*)d_ws;
  float* scores = wsf;             // 32768
  float* ctx    = wsf + 32768;     // 65536   (zeroed with scores: 98304 total)
  float* dh     = wsf + 98304;     // 65536
  float* gpart  = wsf + 163840;    // 8*262144 = 2097152
  float* part   = wsf + 2260992;   // 2*2048000 = 4096000
  unsigned short* encb = (unsigned short*)(wsf + 6356992);   // 33,554,432 bf16
  unsigned short* W2b  = encb + (size_t)BATCH * SEQ * HID;   //  1,048,576 bf16

  zero_ws_kernel<<<96, 256, 0, stream>>>(wsf);   // scores+ctx (atomic targets)

  f2bf_kernel<<<2048, 256, 0, stream>>>(enc, encb, BATCH * SEQ * HID / 8);
  f2bf_kernel<<<512, 256, 0, stream>>>(W2, W2b, HID * HID / 8);
  dh_kernel<<<dim3(4, 64), 256, 0, stream>>>(h, W1, dh);
  scores8_kernel<<<512, 512, 0, stream>>>(encb, W2b, dh, v, scores);
  softmax_kernel<<<64, 512, 0, stream>>>(scores, out + OUT_ATTN);
  context2_kernel<<<dim3(8, 64), 256, 0, stream>>>(encb, out + OUT_ATTN, ctx);
  gates8p_kernel<<<dim3(32, 8), 256, 0, stream>>>(tok, emb, ctx, h, W_ih, W_hh, gpart);
  lstm_kernel<<<dim3(4, 64), 256, 0, stream>>>(gpart, b_ih, b_hh, c, out);
  fc2p_kernel<<<dim3(250, 2), 256, 0, stream>>>(out + OUT_H1, ctx, fcW, part);
  fc_combine_kernel<<<dim3(125, 64), 256, 0, stream>>>(part, fcb, out);
}